// Round 2
// baseline (581.293 us; speedup 1.0000x reference)
//
#include <hip/hip_runtime.h>

// ItemRegressionModel: out[b] = bu + bt + (1/32) * sum_k w[qtu_k, t] * (r[u, qtu_k] - bu - b_item[qtu_k])
// U=I=2000, K=32, B=16384.
//
// Round-1 structure:
//  1) wt_transpose — weight[j][t] is a COLUMN gather in the main kernel:
//     32 random rows x 8KB stride = 32 DRAM page activates per sample,
//     ~524K page misses/iter with caches force-flushed by the harness's 2GB
//     poison fill. Round-0 showed L3 prefetch does NOT stick, so we fix the
//     pattern structurally: build wT[t][j] in the workspace (exact copy,
//     LDS-tiled, both sides coalesced, ~32MB traffic ~ 10us). Main kernel's
//     weight access becomes row-local (one 8KB page per sample), same as
//     rating's already-fine pattern. Rebuilt every launch (ws is re-poisoned).
//  2) irm_kernel — identical math, weight -> wT.

#define U_DIM 2000
#define I_DIM 2000
#define K_DIM 32

// ------------------------------------------------------------- transpose --
// wT[t][j] = weight[j][t]; 32x32 tiles via LDS, +1 pad kills bank conflicts.
__global__ __launch_bounds__(256) void wt_transpose(
    const float* __restrict__ weight,  // (I, I) row-major [j][t]
    float*       __restrict__ wT)      // (I, I) row-major [t][j]
{
    __shared__ float tile[32][33];
    const int tx = threadIdx.x;        // 0..31
    const int ty = threadIdx.y;        // 0..7
    const int row0 = blockIdx.y * 32;  // j block
    const int col0 = blockIdx.x * 32;  // t block

    #pragma unroll
    for (int r = 0; r < 4; ++r) {
        const int j = row0 + ty + 8 * r;
        const int t = col0 + tx;
        if (j < I_DIM && t < I_DIM)
            tile[ty + 8 * r][tx] = weight[(size_t)j * I_DIM + t];  // coalesced read
    }
    __syncthreads();
    #pragma unroll
    for (int r = 0; r < 4; ++r) {
        const int t = col0 + ty + 8 * r;
        const int j = row0 + tx;
        if (t < I_DIM && j < I_DIM)
            wT[(size_t)t * I_DIM + j] = tile[tx][ty + 8 * r];      // coalesced write
    }
}

// ------------------------------------------------------------ main kernel --
template <bool USE_WT>
__global__ __launch_bounds__(256) void irm_kernel(
    const float* __restrict__ rating,   // (U, I)
    const int*   __restrict__ qtus,     // (U, I, K)
    const float* __restrict__ wmat,     // USE_WT ? wT (t-major) : weight (j-major)
    const float* __restrict__ b_user,   // (U,)
    const float* __restrict__ b_item,   // (I,)
    const int*   __restrict__ users,    // (B,)
    const int*   __restrict__ items,    // (B,)
    float*       __restrict__ out,      // (B,)
    int B)
{
    const int tid = blockIdx.x * blockDim.x + threadIdx.x;
    const int b = tid >> 5;      // sample index
    const int k = tid & 31;      // neighborhood slot
    if (b >= B) return;

    const int u = users[b];
    const int t = items[b];

    const size_t qbase = ((size_t)u * I_DIM + t) * (size_t)K_DIM;
    const int j = qtus[qbase + (size_t)k];          // coalesced: lane k -> word k

    // USE_WT: row-local (one 8KB page/sample). Else: column gather (32 pages).
    const float w  = USE_WT ? wmat[(size_t)t * I_DIM + j]
                            : wmat[(size_t)j * I_DIM + t];
    const float r  = rating[(size_t)u * I_DIM + j]; // row-local gather
    const float bu = b_user[u];
    const float bj = b_item[j];                     // 8KB table, cache-resident

    float v = w * (r - bu - bj);

    // reduce across the 32 lanes of this sample (wave=64 holds 2 samples;
    // xor-shuffles with width 32 stay within each half)
    #pragma unroll
    for (int off = 16; off; off >>= 1)
        v += __shfl_xor(v, off, 32);

    if (k == 0)
        out[b] = bu + b_item[t] + v * (1.0f / 32.0f);
}

// ------------------------------------------------------------------ launch --
extern "C" void kernel_launch(void* const* d_in, const int* in_sizes, int n_in,
                              void* d_out, int out_size, void* d_ws, size_t ws_size,
                              hipStream_t stream)
{
    const float* rating = (const float*)d_in[0];
    const int*   qtus   = (const int*)  d_in[1];
    const float* weight = (const float*)d_in[2];
    const float* b_user = (const float*)d_in[3];
    const float* b_item = (const float*)d_in[4];
    const int*   users  = (const int*)  d_in[5];
    const int*   items  = (const int*)  d_in[6];
    float*       out    = (float*)d_out;

    const int B = in_sizes[5];           // users count = 16384
    const int threads = 256;
    const int total = B * 32;
    const int blocks = (total + threads - 1) / threads;

    const size_t wt_bytes = (size_t)I_DIM * I_DIM * sizeof(float);  // 16 MB

    if (ws_size >= wt_bytes) {
        float* wT = (float*)d_ws;
        const dim3 tblk(32, 8);
        const dim3 tgrid((I_DIM + 31) / 32, (I_DIM + 31) / 32);     // 63 x 63
        wt_transpose<<<tgrid, tblk, 0, stream>>>(weight, wT);
        irm_kernel<true><<<blocks, threads, 0, stream>>>(
            rating, qtus, wT, b_user, b_item, users, items, out, B);
    } else {
        // workspace too small: fall back to the verified direct-weight path
        irm_kernel<false><<<blocks, threads, 0, stream>>>(
            rating, qtus, weight, b_user, b_item, users, items, out, B);
    }
}